// Round 4
// baseline (624.394 us; speedup 1.0000x reference)
//
#include <hip/hip_runtime.h>

// ScalingAndSquaring: v <- v + warp(v), 7 steps, (2,3,160,160,160) f32.
// out(d,h,w) = v(d,h,w) + trilinear v(z~w, y~h, x~d)  (self-transposed gather).
// 32(d) x 32(w) tile per h-plane via LDS; gathers run with d-fast lanes.
// Round 4: compiler kept re-serializing gathers (VGPR 52, ~6 loads in flight,
// dur pinned at 116us). Force MLP with inline-asm global_load_dwordx2
// (corner pairs, border folded into wx'), all 48 issued before ONE
// s_waitcnt vmcnt(0) + sched_barrier(0).

constexpr int SZ  = 160;
constexpr int HW  = SZ * SZ;          // 25600
constexpr int DHW = SZ * SZ * SZ;     // 4096000

typedef float vfloat4 __attribute__((ext_vector_type(4)));
typedef float vfloat2 __attribute__((ext_vector_type(2)));

__global__ __launch_bounds__(256, 3)
void warp_step_kernel(const float* __restrict__ src,
                      float* __restrict__ dst,
                      float inScale)
{
    // --- XCD-contiguous swizzle: 8000 blocks, 8 XCDs, 1000 contiguous each ---
    const int wg = (int)blockIdx.x;                 // 0..7999
    const int r  = (wg & 7) * 1000 + (wg >> 3);     // bijective (8000 % 8 == 0)
    const int h0  = r % SZ;                         // H-axis plane
    const int t   = r / SZ;                         // 0..49
    const int bat = t / 25;                         // batch
    const int tt  = t % 25;
    const int a0  = (tt % 5) * 32;                  // D-axis tile base
    const int c0  = (tt / 5) * 32;                  // W-axis tile base

    const float* __restrict__ vb = src + (size_t)bat * 3 * DHW;
    float*       __restrict__ db = dst + (size_t)bat * 3 * DHW;

    // tile[ch][w_local][d_local], stride 33 -> conflict-free in both phases
    __shared__ float tile[3][32][33];

    const int tid = (int)threadIdx.x;

    // --- phase 1: stage own-voxel v tile (scaled), float4 coalesced reads ---
    {
        const int q  = (tid & 7) << 2;   // float4 start within row (w_local)
        const int r0 = tid >> 3;         // 0..31 -> d_local; p -> channel
        #pragma unroll
        for (int p = 0; p < 3; ++p) {
            const vfloat4 vv = *reinterpret_cast<const vfloat4*>(
                &vb[p * DHW + (a0 + r0) * HW + h0 * SZ + c0 + q]);
            tile[p][q + 0][r0] = vv.x * inScale;
            tile[p][q + 1][r0] = vv.y * inScale;
            tile[p][q + 2][r0] = vv.z * inScale;
            tile[p][q + 3][r0] = vv.w * inScale;
        }
    }
    __syncthreads();

    // --- phase 2: d-fast lanes; 4 samples/thread ---
    const int a  = tid & 31;      // d_local  (lane-fast)
    const int cb = tid >> 5;      // 0..7     (w_local base)
    const float gx = (float)(a0 + a);   // d feeds grid_sample's x slot
    const float gy = (float)h0;         // h feeds y slot

    // stage A: all LDS reads
    float v0s[4], v1s[4], v2s[4];
    #pragma unroll
    for (int i = 0; i < 4; ++i) {
        const int c = cb + (i << 3);
        v0s[i] = tile[0][c][a];
        v1s[i] = tile[1][c][a];
        v2s[i] = tile[2][c][a];
    }

    // stage B: coordinate/address/weight math.
    // Corner-pair trick: load (f[xp], f[xp+1]) with xp = min(x0, 158) and use
    // wx' = ix - xp. For x0 <= 158 this is the standard lerp; for x0 == 159,
    // ix == 159.0 exactly so wx' = 1.0 selects .y == f[159]. No selects, no OOB.
    int   o[4][4];                       // [sample][(z,y) corner] element offset
    float wxs[4], wys[4], wzs[4];
    #pragma unroll
    for (int i = 0; i < 4; ++i) {
        const int c = cb + (i << 3);
        const float gz = (float)(c0 + c);
        float ix = ((2.0f * ((gx + v0s[i]) / 159.0f - 0.5f) + 1.0f) * 160.0f - 1.0f) * 0.5f;
        float iy = ((2.0f * ((gy + v1s[i]) / 159.0f - 0.5f) + 1.0f) * 160.0f - 1.0f) * 0.5f;
        float iz = ((2.0f * ((gz + v2s[i]) / 159.0f - 0.5f) + 1.0f) * 160.0f - 1.0f) * 0.5f;
        ix = fminf(fmaxf(ix, 0.0f), 159.0f);
        iy = fminf(fmaxf(iy, 0.0f), 159.0f);
        iz = fminf(fmaxf(iz, 0.0f), 159.0f);
        const float fy = floorf(iy), fz = floorf(iz);
        const int x0 = (int)floorf(ix);
        const int y0 = (int)fy, z0 = (int)fz;
        const int y1 = min(y0 + 1, SZ - 1);
        const int z1 = min(z0 + 1, SZ - 1);
        const int xp = min(x0, SZ - 2);
        o[i][0] = (z0 * SZ + y0) * SZ + xp;
        o[i][1] = (z0 * SZ + y1) * SZ + xp;
        o[i][2] = (z1 * SZ + y0) * SZ + xp;
        o[i][3] = (z1 * SZ + y1) * SZ + xp;
        wxs[i] = ix - (float)xp;
        wys[i] = iy - fy;
        wzs[i] = iz - fz;
    }

    // stage C: issue ALL 48 corner-pair loads via inline asm (volatile ->
    // issue order preserved, compiler cannot consume early), then ONE wait.
    vfloat2 P[4][3][4];
    #pragma unroll
    for (int i = 0; i < 4; ++i) {
        #pragma unroll
        for (int ch = 0; ch < 3; ++ch) {
            #pragma unroll
            for (int k = 0; k < 4; ++k) {
                const float* p = vb + ch * DHW + o[i][k];
                asm volatile("global_load_dwordx2 %0, %1, off"
                             : "=v"(P[i][ch][k]) : "v"(p));
            }
        }
    }
    asm volatile("s_waitcnt vmcnt(0)" ::: "memory");
    __builtin_amdgcn_sched_barrier(0);   // rule #18: keep consumers below

    // stage D+E: interpolate and write back to own LDS slots
    #pragma unroll
    for (int i = 0; i < 4; ++i) {
        const int c = cb + (i << 3);
        const float wx = wxs[i];
        const float wy = wys[i], wz = wzs[i];
        const float wy0 = 1.0f - wy, wz0 = 1.0f - wz;
        const float w00 = wz0 * wy0, w01 = wz0 * wy;
        const float w10 = wz  * wy0, w11 = wz  * wy;
        #pragma unroll
        for (int ch = 0; ch < 3; ++ch) {
            const float s00 = P[i][ch][0].x + wx * (P[i][ch][0].y - P[i][ch][0].x);
            const float s01 = P[i][ch][1].x + wx * (P[i][ch][1].y - P[i][ch][1].x);
            const float s10 = P[i][ch][2].x + wx * (P[i][ch][2].y - P[i][ch][2].x);
            const float s11 = P[i][ch][3].x + wx * (P[i][ch][3].y - P[i][ch][3].x);
            const float res = (s00 * w00 + s01 * w01) + (s10 * w10 + s11 * w11);
            const float own = (ch == 0) ? v0s[i] : (ch == 1) ? v1s[i] : v2s[i];
            tile[ch][c][a] = own + res * inScale;
        }
    }
    __syncthreads();

    // --- phase 3: coalesced float4 nontemporal writes ---
    {
        const int q  = (tid & 7) << 2;
        const int r0 = tid >> 3;
        #pragma unroll
        for (int p = 0; p < 3; ++p) {
            vfloat4 vv;
            vv.x = tile[p][q + 0][r0];
            vv.y = tile[p][q + 1][r0];
            vv.z = tile[p][q + 2][r0];
            vv.w = tile[p][q + 3][r0];
            __builtin_nontemporal_store(vv, reinterpret_cast<vfloat4*>(
                &db[p * DHW + (a0 + r0) * HW + h0 * SZ + c0 + q]));
        }
    }
}

extern "C" void kernel_launch(void* const* d_in, const int* in_sizes, int n_in,
                              void* d_out, int out_size, void* d_ws, size_t ws_size,
                              hipStream_t stream)
{
    const float* vin = (const float*)d_in[0];
    float* out = (float*)d_out;
    float* ws  = (float*)d_ws;   // needs >= 2*3*160^3*4 = 98,304,000 bytes

    dim3 grid(8000), block(256);
    // 7 steps, ping-pong so the final result lands in d_out.
    warp_step_kernel<<<grid, block, 0, stream>>>(vin, out, 1.0f / 128.0f); // v1
    warp_step_kernel<<<grid, block, 0, stream>>>(out, ws,  1.0f);          // v2
    warp_step_kernel<<<grid, block, 0, stream>>>(ws,  out, 1.0f);          // v3
    warp_step_kernel<<<grid, block, 0, stream>>>(out, ws,  1.0f);          // v4
    warp_step_kernel<<<grid, block, 0, stream>>>(ws,  out, 1.0f);          // v5
    warp_step_kernel<<<grid, block, 0, stream>>>(out, ws,  1.0f);          // v6
    warp_step_kernel<<<grid, block, 0, stream>>>(ws,  out, 1.0f);          // v7
}